// Round 7
// baseline (39.010 us; speedup 1.0000x reference)
//
#include <hip/hip_runtime.h>
#include <hip/hip_bf16.h>

// DataTerm layer: out[b,h,w,:] = {u,v} - ALPHA * dataTerm * {dI1_dy, dI1_dx}
// where dataTerm = bilinear_sample(I1, normalized-coords-misused-as-pixels) - I2.
// Reference quirks preserved:
//  - (dy,dx) bound as (grad_x,grad_y): u uses the ROW diff, v the COL diff.
//  - warp normalizes coords to [-1,1] then samples them as raw pixels, so all
//    bilinear corners land in the 3x3 top-left patch -> preload 9 uniform
//    values, select with cndmask (round-2 win).
// Round-7: dual-group MLP. Each thread handles TWO 4px groups 16 images
// apart (constant offset) -> 12 independent loads in flight per thread
// (2x round 2) while keeping the proven 4px store layout (round 5/6
// post-mortem: 8px stores fragment -> WRITE 109MB; 4px stores merge ->
// WRITE 66MB; NT stores neutral-to-negative on FETCH -> cached stores).
// Diagnosis driving this: rounds 2 & 6 both sit at ~3.9 TB/s effective with
// VALUBusy ~24%, occupancy ~68% -> latency/MLP-bound, not BW-bound.

#define ALPHA 0.1f

constexpr int B = 32, H = 512, W = 512;
constexpr int HW = H * W;                       // 262144
constexpr size_t OFF_B = (size_t)(B / 2) * HW;  // 16 images ahead

__device__ __forceinline__ void compute4(
    const float4& i1v, const float4& dn, const float4& i2v,
    const float4& f0, const float4& f1, float i1r,
    int h, int w4, bool has_dn, const float S[9], float on[8])
{
    float uarr[4] = { f0.x, f0.z, f1.x, f1.z };
    float varr[4] = { f0.y, f0.w, f1.y, f1.w };
    float i1a[5]  = { i1v.x, i1v.y, i1v.z, i1v.w, i1r };
    float i1d[4]  = { dn.x, dn.y, dn.z, dn.w };
    float i2a[4]  = { i2v.x, i2v.y, i2v.z, i2v.w };

    const float sx = 2.0f / (W - 1.0f);
    const float sy = 2.0f / (H - 1.0f);

#pragma unroll
    for (int j = 0; j < 4; ++j) {
        int w = w4 + j;
        float u = uarr[j], v = varr[j];
        float x = ((float)w + 0.5f * u) * sx - 1.0f;
        float y = ((float)h + 0.5f * v) * sy - 1.0f;
        float x0f = floorf(x), y0f = floorf(y);
        float x1f = x0f + 1.0f, y1f = y0f + 1.0f;
        x0f = fminf(fmaxf(x0f, 0.0f), W - 1.0f);
        x1f = fminf(fmaxf(x1f, 0.0f), W - 1.0f);
        y0f = fminf(fmaxf(y0f, 0.0f), H - 1.0f);
        y1f = fminf(fmaxf(y1f, 0.0f), H - 1.0f);
        int x0i = (int)x0f, x1i = (int)x1f;   // in {0,1} / {0,1,2}
        int y0i = (int)y0f, y1i = (int)y1f;

        // Select corner values from the preloaded 3x3 patch (pure VALU).
        float r0 = (x0i == 0) ? S[0] : S[1];
        float r1 = (x0i == 0) ? S[3] : S[4];
        float r2 = (x0i == 0) ? S[6] : S[7];
        float q0 = (x1i == 0) ? S[0] : ((x1i == 1) ? S[1] : S[2]);
        float q1 = (x1i == 0) ? S[3] : ((x1i == 1) ? S[4] : S[5]);
        float q2 = (x1i == 0) ? S[6] : ((x1i == 1) ? S[7] : S[8]);
        float Ia  = (y0i == 0) ? r0 : r1;
        float Ibv = (y1i == 0) ? r0 : ((y1i == 1) ? r1 : r2);
        float Ic  = (y0i == 0) ? q0 : q1;
        float Id  = (y1i == 0) ? q0 : ((y1i == 1) ? q1 : q2);

        float wa = (x1f - x) * (y1f - y);
        float wb = (x1f - x) * (y - y0f);
        float wc = (x - x0f) * (y1f - y);
        float wd = (x - x0f) * (y - y0f);
        float warped = wa * Ia + wb * Ibv + wc * Ic + wd * Id;
        float dt = warped - i2a[j];
        float gdy = has_dn ? (i1d[j] - i1a[j]) : 0.0f;          // row diff -> u
        float gdx = (w < W - 1) ? (i1a[j + 1] - i1a[j]) : 0.0f; // col diff -> v
        on[2 * j]     = u - ALPHA * dt * gdy;
        on[2 * j + 1] = v - ALPHA * dt * gdx;
    }
}

__global__ __launch_bounds__(256) void dataterm_kernel(
    const float* __restrict__ I1,
    const float* __restrict__ I2,
    const float* __restrict__ flow,
    float* __restrict__ out)
{
    int idx = blockIdx.x * 256 + threadIdx.x;   // [0, B/2 * H * W/4)
    int w4  = (idx & (W / 4 - 1)) * 4;          // 128 groups/row
    int h   = (idx >> 7) & (H - 1);
    int bA  = idx >> 16;                        // 65536 groups/image; uniform/block

    const float* I1A = I1 + (size_t)bA * HW;
    const float* I1B = I1A + OFF_B;
    // Block-uniform 3x3 corner patches (scalar loads).
    float SA[9] = { I1A[0],     I1A[1],         I1A[2],
                    I1A[W],     I1A[W + 1],     I1A[W + 2],
                    I1A[2 * W], I1A[2 * W + 1], I1A[2 * W + 2] };
    float SB[9] = { I1B[0],     I1B[1],         I1B[2],
                    I1B[W],     I1B[W + 1],     I1B[W + 2],
                    I1B[2 * W], I1B[2 * W + 1], I1B[2 * W + 2] };

    size_t roA = (size_t)(bA * H + h) * W + w4;
    size_t roB = roA + OFF_B;
    bool has_dn = (h < H - 1);
    bool has_r  = (w4 + 4 < W);

    // Issue all 12 independent loads up front (MLP).
    float4 a_i1 = *(const float4*)(I1 + roA);
    float4 b_i1 = *(const float4*)(I1 + roB);
    float4 a_i2 = *(const float4*)(I2 + roA);
    float4 b_i2 = *(const float4*)(I2 + roB);
    float4 a_f0 = *(const float4*)(flow + 2 * roA);
    float4 a_f1 = *(const float4*)(flow + 2 * roA + 4);
    float4 b_f0 = *(const float4*)(flow + 2 * roB);
    float4 b_f1 = *(const float4*)(flow + 2 * roB + 4);
    float4 zero4 = make_float4(0.f, 0.f, 0.f, 0.f);
    float4 a_dn = has_dn ? *(const float4*)(I1 + roA + W) : zero4;
    float4 b_dn = has_dn ? *(const float4*)(I1 + roB + W) : zero4;
    float  a_r  = has_r ? I1[roA + 4] : 0.0f;
    float  b_r  = has_r ? I1[roB + 4] : 0.0f;

    float onA[8], onB[8];
    compute4(a_i1, a_dn, a_i2, a_f0, a_f1, a_r, h, w4, has_dn, SA, onA);
    compute4(b_i1, b_dn, b_i2, b_f0, b_f1, b_r, h, w4, has_dn, SB, onB);

    float* opA = out + 2 * roA;
    float* opB = out + 2 * roB;
    *(float4*)(opA)     = make_float4(onA[0], onA[1], onA[2], onA[3]);
    *(float4*)(opA + 4) = make_float4(onA[4], onA[5], onA[6], onA[7]);
    *(float4*)(opB)     = make_float4(onB[0], onB[1], onB[2], onB[3]);
    *(float4*)(opB + 4) = make_float4(onB[4], onB[5], onB[6], onB[7]);
}

extern "C" void kernel_launch(void* const* d_in, const int* in_sizes, int n_in,
                              void* d_out, int out_size, void* d_ws, size_t ws_size,
                              hipStream_t stream) {
    const float* I1   = (const float*)d_in[0];
    const float* I2   = (const float*)d_in[1];
    const float* flow = (const float*)d_in[2];
    float* out = (float*)d_out;

    int total_threads = (B / 2) * H * (W / 4);  // 1,048,576
    int block = 256;
    int grid = total_threads / block;           // 4096
    dataterm_kernel<<<grid, block, 0, stream>>>(I1, I2, flow, out);
}

// Round 8
// 36.049 us; speedup vs baseline: 1.0821x; 1.0821x over previous
//
#include <hip/hip_runtime.h>
#include <hip/hip_bf16.h>

// DataTerm layer: out[b,h,w,:] = {u,v} - ALPHA * dataTerm * {dI1_dy, dI1_dx}
// where dataTerm = bilinear_sample(I1, normalized-coords-misused-as-pixels) - I2.
// Reference quirks preserved:
//  - (dy,dx) bound as (grad_x,grad_y): u uses the ROW diff, v the COL diff.
//  - warp normalizes coords to [-1,1] then samples them as raw pixels, so all
//    bilinear corners land in the 3x3 top-left patch -> preload 9 uniform
//    values, select with cndmask (round-2 win: removed gather latency chain).
//
// FINAL (= round-2 config, best measured: 36.1 us). Session A/B evidence:
//  - 4px/thread, 24 VGPR, occupancy 68%: 36.1 us  <- this kernel
//  - 8px/thread: store fragmentation (WRITE 66->109 MB), 46.2 us
//  - NT stores: LLC-bypass, FETCH rose, 38-59 us
//  - 2px/thread + NT: 38.3 us
//  - dual-image MLP (44 VGPR, occupancy 44%): 39.0 us
// Steady state: FETCH 74 MB + WRITE 66 MB HBM + ~95 MB LLC-served =
// combined-tier ~6.5 TB/s at 36.1 us, at the 6.3 TB/s copy ceiling.

#define ALPHA 0.1f

constexpr int B = 32, H = 512, W = 512;

__global__ __launch_bounds__(256) void dataterm_kernel(
    const float* __restrict__ I1,
    const float* __restrict__ I2,
    const float* __restrict__ flow,
    float* __restrict__ out)
{
    // 256 blocks per batch image; b is wave-uniform -> s_loads for the patch.
    int b   = blockIdx.x >> 8;
    int idx = ((blockIdx.x & 255) << 8) | threadIdx.x;  // pixel-group in image
    int w4  = (idx & (W / 4 - 1)) * 4;
    int h   = idx >> 7;

    const float* I1b = I1 + (size_t)b * (H * W);
    // Block-uniform 3x3 corner patch (all bilinear corners live here).
    float S00 = I1b[0],     S01 = I1b[1],         S02 = I1b[2];
    float S10 = I1b[W],     S11 = I1b[W + 1],     S12 = I1b[W + 2];
    float S20 = I1b[2 * W], S21 = I1b[2 * W + 1], S22 = I1b[2 * W + 2];

    size_t rowoff = (size_t)(b * H + h) * W + w4;

    float4 i1v = *(const float4*)(I1 + rowoff);
    float4 i2v = *(const float4*)(I2 + rowoff);
    float4 i1dn = make_float4(0.f, 0.f, 0.f, 0.f);
    bool has_dn = (h < H - 1);
    if (has_dn) i1dn = *(const float4*)(I1 + rowoff + W);
    float i1r4 = (w4 + 4 < W) ? I1[rowoff + 4] : 0.0f;

    float4 f0 = *(const float4*)(flow + 2 * rowoff);       // u0 v0 u1 v1
    float4 f1 = *(const float4*)(flow + 2 * rowoff + 4);   // u2 v2 u3 v3

    float uarr[4] = { f0.x, f0.z, f1.x, f1.z };
    float varr[4] = { f0.y, f0.w, f1.y, f1.w };
    float i1a[5]  = { i1v.x, i1v.y, i1v.z, i1v.w, i1r4 };
    float i1d[4]  = { i1dn.x, i1dn.y, i1dn.z, i1dn.w };
    float i2a[4]  = { i2v.x, i2v.y, i2v.z, i2v.w };

    const float sx = 2.0f / (W - 1.0f);
    const float sy = 2.0f / (H - 1.0f);

    float on[8];
#pragma unroll
    for (int j = 0; j < 4; ++j) {
        int w = w4 + j;
        float u = uarr[j], v = varr[j];
        float x = ((float)w + 0.5f * u) * sx - 1.0f;
        float y = ((float)h + 0.5f * v) * sy - 1.0f;
        float x0f = floorf(x), y0f = floorf(y);
        float x1f = x0f + 1.0f, y1f = y0f + 1.0f;
        x0f = fminf(fmaxf(x0f, 0.0f), W - 1.0f);
        x1f = fminf(fmaxf(x1f, 0.0f), W - 1.0f);
        y0f = fminf(fmaxf(y0f, 0.0f), H - 1.0f);
        y1f = fminf(fmaxf(y1f, 0.0f), H - 1.0f);
        int x0i = (int)x0f, x1i = (int)x1f;   // in {0,1} / {0,1,2}
        int y0i = (int)y0f, y1i = (int)y1f;

        // Select corner values from the preloaded 3x3 patch (pure VALU).
        float r0 = (x0i == 0) ? S00 : S01;
        float r1 = (x0i == 0) ? S10 : S11;
        float r2 = (x0i == 0) ? S20 : S21;
        float q0 = (x1i == 0) ? S00 : ((x1i == 1) ? S01 : S02);
        float q1 = (x1i == 0) ? S10 : ((x1i == 1) ? S11 : S12);
        float q2 = (x1i == 0) ? S20 : ((x1i == 1) ? S21 : S22);
        float Ia  = (y0i == 0) ? r0 : r1;
        float Ibv = (y1i == 0) ? r0 : ((y1i == 1) ? r1 : r2);
        float Ic  = (y0i == 0) ? q0 : q1;
        float Id  = (y1i == 0) ? q0 : ((y1i == 1) ? q1 : q2);

        float wa = (x1f - x) * (y1f - y);
        float wb = (x1f - x) * (y - y0f);
        float wc = (x - x0f) * (y1f - y);
        float wd = (x - x0f) * (y - y0f);
        float warped = wa * Ia + wb * Ibv + wc * Ic + wd * Id;
        float dt = warped - i2a[j];
        float gdy = has_dn ? (i1d[j] - i1a[j]) : 0.0f;          // row diff -> u
        float gdx = (w < W - 1) ? (i1a[j + 1] - i1a[j]) : 0.0f; // col diff -> v
        on[2 * j]     = u - ALPHA * dt * gdy;
        on[2 * j + 1] = v - ALPHA * dt * gdx;
    }

    *(float4*)(out + 2 * rowoff)     = make_float4(on[0], on[1], on[2], on[3]);
    *(float4*)(out + 2 * rowoff + 4) = make_float4(on[4], on[5], on[6], on[7]);
}

extern "C" void kernel_launch(void* const* d_in, const int* in_sizes, int n_in,
                              void* d_out, int out_size, void* d_ws, size_t ws_size,
                              hipStream_t stream) {
    const float* I1   = (const float*)d_in[0];
    const float* I2   = (const float*)d_in[1];
    const float* flow = (const float*)d_in[2];
    float* out = (float*)d_out;

    int total_threads = B * H * (W / 4);           // 2,097,152
    int block = 256;
    int grid = total_threads / block;              // 8192
    dataterm_kernel<<<grid, block, 0, stream>>>(I1, I2, flow, out);
}